// Round 1
// baseline (4272.661 us; speedup 1.0000x reference)
//
#include <hip/hip_runtime.h>
#include <hip/hip_bf16.h>

typedef __hip_bfloat16 bf16;

#define NH 16
#define NB 2
#define SS 2048
#define EE 1024
#define DH 64
#define DV 128
#define MM (NB*SS)          // 4096
#define LAM0 0.7778701f     // 0.8 - 0.6*exp(-0.3*11)
#define LN_EPS 1e-5f

// ---------------- wave reductions (64 lanes) ----------------
__device__ inline float wsum(float v) {
#pragma unroll
    for (int m = 32; m >= 1; m >>= 1) v += __shfl_xor(v, m, 64);
    return v;
}
__device__ inline float wmax(float v) {
#pragma unroll
    for (int m = 32; m >= 1; m >>= 1) v = fmaxf(v, __shfl_xor(v, m, 64));
    return v;
}

// ---------------- typed load/store helpers ----------------
__device__ inline void load8(const float* p, float* d) {
    const float4* q = reinterpret_cast<const float4*>(p);
    float4 a = q[0], b = q[1];
    d[0]=a.x; d[1]=a.y; d[2]=a.z; d[3]=a.w; d[4]=b.x; d[5]=b.y; d[6]=b.z; d[7]=b.w;
}
__device__ inline void load8(const bf16* p, float* d) {
    uint4 u = *reinterpret_cast<const uint4*>(p);
    const ushort* s = reinterpret_cast<const ushort*>(&u);
#pragma unroll
    for (int j = 0; j < 8; ++j) {
        unsigned v = ((unsigned)s[j]) << 16;
        d[j] = __uint_as_float(v);
    }
}
__device__ inline void stC(float* p, float v) { *p = v; }
__device__ inline void stC(bf16* p, float v) { *p = __float2bfloat16(v); }

// ---------------- generic tiled GEMM: C[M x N] = A[M x K] @ B[K x N] ----------------
// tile 64x64, K-tile 32, 256 threads, each thread 4x4 outputs. M fixed multiple of 64.
template<typename AT, typename CT>
__global__ __launch_bounds__(256) void gemm64(const AT* __restrict__ A,
                                              const float* __restrict__ Bw,
                                              CT* __restrict__ C, int N, int K) {
    __shared__ float As[64][33];
    __shared__ float Bs[32][65];
    int t  = threadIdx.x;
    int bx = blockIdx.x, by = blockIdx.y;
    int row0 = by * 64, col0 = bx * 64;
    int tx = t & 15, ty = t >> 4;
    int arow = t >> 2, acol = (t & 3) * 8;   // A tile: 64 x 32
    int brow = t >> 3, bcol = (t & 7) * 8;   // B tile: 32 x 64

    float acc[4][4] = {};
    for (int k0 = 0; k0 < K; k0 += 32) {
        float tmp[8];
        load8(&A[(size_t)(row0 + arow) * K + k0 + acol], tmp);
#pragma unroll
        for (int j = 0; j < 8; ++j) As[arow][acol + j] = tmp[j];
        load8(&Bw[(size_t)(k0 + brow) * N + col0 + bcol], tmp);
#pragma unroll
        for (int j = 0; j < 8; ++j) Bs[brow][bcol + j] = tmp[j];
        __syncthreads();
#pragma unroll
        for (int kk = 0; kk < 32; ++kk) {
            float a[4], b[4];
#pragma unroll
            for (int i = 0; i < 4; ++i) a[i] = As[ty * 4 + i][kk];
#pragma unroll
            for (int j = 0; j < 4; ++j) b[j] = Bs[kk][tx * 4 + j];
#pragma unroll
            for (int i = 0; i < 4; ++i)
#pragma unroll
                for (int j = 0; j < 4; ++j) acc[i][j] += a[i] * b[j];
        }
        __syncthreads();
    }
#pragma unroll
    for (int i = 0; i < 4; ++i)
#pragma unroll
        for (int j = 0; j < 4; ++j)
            stC(&C[(size_t)(row0 + ty * 4 + i) * N + col0 + tx * 4 + j], acc[i][j]);
}

// ---------------- fused differential attention + LayerNorm ----------------
// grid: NB*NH*(SS/4) blocks, 256 threads = 4 waves; wave w handles q-row qg*4+w.
__global__ __launch_bounds__(256) void attn_kernel(
        const bf16* __restrict__ q1b, const bf16* __restrict__ q2b,
        const bf16* __restrict__ k1b, const bf16* __restrict__ k2b,
        const bf16* __restrict__ vb,
        const float* __restrict__ lq1, const float* __restrict__ lk1,
        const float* __restrict__ lq2, const float* __restrict__ lk2,
        bf16* __restrict__ merged) {
    __shared__ bf16 k1s[64][64];
    __shared__ bf16 k2s[64][64];
    __shared__ bf16 vs[64][128];
    __shared__ float qs1[4][64], qs2[4][64];
    __shared__ float p1s[4][64], p2s[4][64];

    int bid = blockIdx.x;
    int qg  = bid % (SS / 4);
    int bh  = bid / (SS / 4);
    int h   = bh % NH, b = bh / NH;
    int t   = threadIdx.x;
    int w   = t >> 6, l = t & 63;
    int qi  = qg * 4 + w;

    // lambda for this head (each wave computes redundantly; 64-elem dots)
    float lp1 = lq1[h * DH + l] * lk1[h * DH + l];
    float lp2 = lq2[h * DH + l] * lk2[h * DH + l];
    float lam = __expf(wsum(lp1)) - __expf(wsum(lp2)) + LAM0;

    // load this wave's q rows into LDS (f32)
    size_t qoff = ((size_t)b * SS + qi) * EE + h * DH;
    qs1[w][l] = __bfloat162float(q1b[qoff + l]);
    qs2[w][l] = __bfloat162float(q2b[qoff + l]);

    float m1 = -1e30f, m2 = -1e30f, l1 = 0.f, l2 = 0.f;
    float acc1[2] = {0.f, 0.f}, acc2[2] = {0.f, 0.f};
    const float scale = 0.125f;  // 1/sqrt(64)

    int ntiles = (qg * 4) / 64 + 1;   // group of 4 never straddles a 64 boundary
    for (int kt = 0; kt < ntiles; ++kt) {
        int k0 = kt * 64;
        __syncthreads();   // previous tile's PV done before overwrite
        {   // stage K1,K2 tiles (64x64 bf16): thread loads 16 bf16 (2x uint4)
            int r = t >> 2, c = (t & 3) * 16;
            size_t g = ((size_t)b * SS + k0 + r) * EE + h * DH + c;
            *reinterpret_cast<uint4*>(&k1s[r][c])     = *reinterpret_cast<const uint4*>(&k1b[g]);
            *reinterpret_cast<uint4*>(&k1s[r][c + 8]) = *reinterpret_cast<const uint4*>(&k1b[g + 8]);
            *reinterpret_cast<uint4*>(&k2s[r][c])     = *reinterpret_cast<const uint4*>(&k2b[g]);
            *reinterpret_cast<uint4*>(&k2s[r][c + 8]) = *reinterpret_cast<const uint4*>(&k2b[g + 8]);
        }
        {   // stage V tile (64x128 bf16): thread loads 32 bf16 (4x uint4)
            int r = t >> 2, c0 = (t & 3) * 32;
            size_t g = ((size_t)b * SS + k0 + r) * (2 * EE) + h * DV + c0;
#pragma unroll
            for (int j = 0; j < 4; ++j)
                *reinterpret_cast<uint4*>(&vs[r][c0 + j * 8]) =
                    *reinterpret_cast<const uint4*>(&vb[g + j * 8]);
        }
        __syncthreads();

        // scores for key = k0 + l  (lane-staggered dd walk: conflict-free)
        int key = k0 + l;
        float s1 = -1e30f, s2 = -1e30f;
        if (key <= qi) {
            float t1 = 0.f, t2 = 0.f;
#pragma unroll 8
            for (int i = 0; i < 64; ++i) {
                int dd = (l + i) & 63;
                t1 += qs1[w][dd] * __bfloat162float(k1s[l][dd]);
                t2 += qs2[w][dd] * __bfloat162float(k2s[l][dd]);
            }
            s1 = t1 * scale; s2 = t2 * scale;
        }
        // online softmax update, stream 1
        float m1n = fmaxf(m1, wmax(s1));
        float sc1 = __expf(m1 - m1n);
        float p1  = (s1 > -1e29f) ? __expf(s1 - m1n) : 0.f;
        l1 = l1 * sc1 + wsum(p1);
        acc1[0] *= sc1; acc1[1] *= sc1; m1 = m1n;
        // stream 2
        float m2n = fmaxf(m2, wmax(s2));
        float sc2 = __expf(m2 - m2n);
        float p2  = (s2 > -1e29f) ? __expf(s2 - m2n) : 0.f;
        l2 = l2 * sc2 + wsum(p2);
        acc2[0] *= sc2; acc2[1] *= sc2; m2 = m2n;

        p1s[w][l] = p1;  p2s[w][l] = p2;   // wave-local, lockstep: no barrier needed

        // PV accumulate: lane owns V columns l and l+64
#pragma unroll 8
        for (int k = 0; k < 64; ++k) {
            float pp1 = p1s[w][k], pp2 = p2s[w][k];
            float v0 = __bfloat162float(vs[k][l]);
            float v1 = __bfloat162float(vs[k][l + 64]);
            acc1[0] += pp1 * v0; acc1[1] += pp1 * v1;
            acc2[0] += pp2 * v0; acc2[1] += pp2 * v1;
        }
    }

    // combine, LayerNorm over 128 dims (wave-wide), scale, store merged (B,S,2E)
    float o0 = acc1[0] / l1 - lam * acc2[0] / l2;
    float o1 = acc1[1] / l1 - lam * acc2[1] / l2;
    float mu = wsum(o0 + o1) * (1.f / 128.f);
    float d0 = o0 - mu, d1 = o1 - mu;
    float var = wsum(d0 * d0 + d1 * d1) * (1.f / 128.f);
    float sc = rsqrtf(var + LN_EPS) * (1.f - LAM0);
    size_t moff = ((size_t)b * SS + qi) * (2 * EE) + h * DV;
    merged[moff + l]      = __float2bfloat16(d0 * sc);
    merged[moff + l + 64] = __float2bfloat16(d1 * sc);
}

// ---------------- launch ----------------
extern "C" void kernel_launch(void* const* d_in, const int* in_sizes, int n_in,
                              void* d_out, int out_size, void* d_ws, size_t ws_size,
                              hipStream_t stream) {
    (void)in_sizes; (void)n_in; (void)out_size; (void)ws_size;
    const float* x   = (const float*)d_in[0];
    const float* Wq1 = (const float*)d_in[1];
    const float* Wq2 = (const float*)d_in[2];
    const float* Wk1 = (const float*)d_in[3];
    const float* Wk2 = (const float*)d_in[4];
    const float* Wv  = (const float*)d_in[5];
    const float* Wo  = (const float*)d_in[6];
    const float* lq1 = (const float*)d_in[7];
    const float* lk1 = (const float*)d_in[8];
    const float* lq2 = (const float*)d_in[9];
    const float* lk2 = (const float*)d_in[10];
    float* out = (float*)d_out;

    char* ws = (char*)d_ws;
    const size_t MB = 1ull << 20;
    bf16* q1  = (bf16*)(ws);             // 4096x1024 bf16 = 8MB
    bf16* q2  = (bf16*)(ws + 8  * MB);
    bf16* k1  = (bf16*)(ws + 16 * MB);
    bf16* k2  = (bf16*)(ws + 24 * MB);
    bf16* v   = (bf16*)(ws + 32 * MB);   // 4096x2048 bf16 = 16MB
    bf16* mg  = (bf16*)(ws + 48 * MB);   // 4096x2048 bf16 = 16MB

    dim3 blk(256);
    // projections: x(4096x1024) @ W -> bf16
    gemm64<float, bf16><<<dim3(16, 64), blk, 0, stream>>>(x, Wq1, q1, 1024, 1024);
    gemm64<float, bf16><<<dim3(16, 64), blk, 0, stream>>>(x, Wq2, q2, 1024, 1024);
    gemm64<float, bf16><<<dim3(16, 64), blk, 0, stream>>>(x, Wk1, k1, 1024, 1024);
    gemm64<float, bf16><<<dim3(16, 64), blk, 0, stream>>>(x, Wk2, k2, 1024, 1024);
    gemm64<float, bf16><<<dim3(32, 64), blk, 0, stream>>>(x, Wv,  v,  2048, 1024);
    // fused differential attention + LN -> merged bf16 (B,S,2E)
    attn_kernel<<<dim3(NB * NH * (SS / 4)), blk, 0, stream>>>(
        q1, q2, k1, k2, v, lq1, lk1, lq2, lk2, mg);
    // out = merged(4096x2048) @ Wo(2048x1024) -> f32
    gemm64<bf16, float><<<dim3(16, 64), blk, 0, stream>>>(mg, Wo, out, 1024, 2048);
}

// Round 2
// 1468.003 us; speedup vs baseline: 2.9105x; 2.9105x over previous
//
#include <hip/hip_runtime.h>
#include <hip/hip_bf16.h>

typedef __hip_bfloat16 bf16;
typedef __bf16 bf16x8 __attribute__((ext_vector_type(8)));
typedef float f32x4 __attribute__((ext_vector_type(4)));
typedef unsigned short ushort_t;

#define NH 16
#define NB 2
#define SS 2048
#define EE 1024
#define DH 64
#define DV 128
#define LAM0 0.7778701f     // 0.8 - 0.6*exp(-0.3*11)
#define LN_EPS 1e-5f
#define PSTR 72             // padded LDS row stride (bf16 elems): 144B = 16B*9

// ---------------- typed load/store helpers (SIMT GEMM path) ----------------
__device__ inline void load8(const float* p, float* d) {
    const float4* q = reinterpret_cast<const float4*>(p);
    float4 a = q[0], b = q[1];
    d[0]=a.x; d[1]=a.y; d[2]=a.z; d[3]=a.w; d[4]=b.x; d[5]=b.y; d[6]=b.z; d[7]=b.w;
}
__device__ inline void load8(const bf16* p, float* d) {
    uint4 u = *reinterpret_cast<const uint4*>(p);
    const ushort_t* s = reinterpret_cast<const ushort_t*>(&u);
#pragma unroll
    for (int j = 0; j < 8; ++j) {
        unsigned v = ((unsigned)s[j]) << 16;
        d[j] = __uint_as_float(v);
    }
}
__device__ inline void stC(float* p, float v) { *p = v; }
__device__ inline void stC(bf16* p, float v) { *p = __float2bfloat16(v); }

// ---------------- generic tiled GEMM (unchanged from R0, correct) ----------------
template<typename AT, typename CT>
__global__ __launch_bounds__(256) void gemm64(const AT* __restrict__ A,
                                              const float* __restrict__ Bw,
                                              CT* __restrict__ C, int N, int K) {
    __shared__ float As[64][33];
    __shared__ float Bs[32][65];
    int t  = threadIdx.x;
    int bx = blockIdx.x, by = blockIdx.y;
    int row0 = by * 64, col0 = bx * 64;
    int tx = t & 15, ty = t >> 4;
    int arow = t >> 2, acol = (t & 3) * 8;
    int brow = t >> 3, bcol = (t & 7) * 8;

    float acc[4][4] = {};
    for (int k0 = 0; k0 < K; k0 += 32) {
        float tmp[8];
        load8(&A[(size_t)(row0 + arow) * K + k0 + acol], tmp);
#pragma unroll
        for (int j = 0; j < 8; ++j) As[arow][acol + j] = tmp[j];
        load8(&Bw[(size_t)(k0 + brow) * N + col0 + bcol], tmp);
#pragma unroll
        for (int j = 0; j < 8; ++j) Bs[brow][bcol + j] = tmp[j];
        __syncthreads();
#pragma unroll
        for (int kk = 0; kk < 32; ++kk) {
            float a[4], b[4];
#pragma unroll
            for (int i = 0; i < 4; ++i) a[i] = As[ty * 4 + i][kk];
#pragma unroll
            for (int j = 0; j < 4; ++j) b[j] = Bs[kk][tx * 4 + j];
#pragma unroll
            for (int i = 0; i < 4; ++i)
#pragma unroll
                for (int j = 0; j < 4; ++j) acc[i][j] += a[i] * b[j];
        }
        __syncthreads();
    }
#pragma unroll
    for (int i = 0; i < 4; ++i)
#pragma unroll
        for (int j = 0; j < 4; ++j)
            stC(&C[(size_t)(row0 + ty * 4 + i) * N + col0 + tx * 4 + j], acc[i][j]);
}

// ---------------- MFMA differential flash attention + LayerNorm ----------------
// Block: 64 q-rows of one (b,h); 4 waves x 16 rows. 64-key tiles.
// S^T = K·Q^T via mfma_f32_16x16x32_bf16 (A=K from global, B=Q regs).
//   lane (g=l>>4, c=l&15) reg r holds S^T[key = kb*16+4g+r][q = w*16+c].
// P -> per-wave LDS [16][PSTR]; V transposed into Vt[128][PSTR].
// PV: A=P (m=q=c, k=8g+j+32ks), B=Vt (n=vcol=c, k contiguous keys).
//   O: lane reg r holds O[q = 4g+r][vcol = c+16*vb].
__global__ __launch_bounds__(256) void attn_mfma(
        const bf16* __restrict__ q1b, const bf16* __restrict__ q2b,
        const bf16* __restrict__ k1b, const bf16* __restrict__ k2b,
        const bf16* __restrict__ vgl,
        const float* __restrict__ lq1, const float* __restrict__ lk1,
        const float* __restrict__ lq2, const float* __restrict__ lk2,
        bf16* __restrict__ merged) {
    __shared__ ushort_t Vt[DV][PSTR];        // [vcol][key]
    __shared__ ushort_t P1s[4][16][PSTR];    // per-wave [q][key]
    __shared__ ushort_t P2s[4][16][PSTR];

    const int t = threadIdx.x;
    const int w = t >> 6, l = t & 63;
    const int g = l >> 4, c = l & 15;

    const int bid = blockIdx.x;
    const int qt  = (SS / 64 - 1) - (bid >> 5);   // qt-descending for load balance
    const int bh  = bid & 31;
    const int h   = bh & (NH - 1), b = bh >> 4;
    const int q0  = qt * 64;

    // lambda for this head
    float lam;
    {
        float s1 = lq1[h * DH + l] * lk1[h * DH + l];
        float s2 = lq2[h * DH + l] * lk2[h * DH + l];
#pragma unroll
        for (int m = 32; m >= 1; m >>= 1) {
            s1 += __shfl_xor(s1, m, 64);
            s2 += __shfl_xor(s2, m, 64);
        }
        lam = __expf(s1) - __expf(s2) + LAM0;
    }

    // Q fragments in registers: Q[q0+w*16+c][8g+j+32ks]
    bf16x8 qf1[2], qf2[2];
    {
        size_t qrow = (size_t)(b * SS + q0 + w * 16 + c) * EE + h * DH;
#pragma unroll
        for (int ks = 0; ks < 2; ++ks) {
            qf1[ks] = *reinterpret_cast<const bf16x8*>(&q1b[qrow + 8 * g + 32 * ks]);
            qf2[ks] = *reinterpret_cast<const bf16x8*>(&q2b[qrow + 8 * g + 32 * ks]);
        }
    }

    f32x4 acc1[8], acc2[8];
    const f32x4 fz = {0.f, 0.f, 0.f, 0.f};
#pragma unroll
    for (int i = 0; i < 8; ++i) { acc1[i] = fz; acc2[i] = fz; }
    float m1 = -1e30f, m2 = -1e30f, l1 = 0.f, l2 = 0.f;
    const float scale = 0.125f;   // 1/sqrt(64)

    for (int kt = 0; kt <= qt; ++kt) {
        const int k0 = kt * 64;
        const bool diag = (kt == qt);
        __syncthreads();   // prior tile's PV reads complete

        // ---- stage Vt: transpose V[64 keys][128 vcols] -> Vt[vcol][key] ----
        {
            const int k4 = (t & 15) * 4;
            const int c8 = (t >> 4) * 8;
            uint4 va[4];
#pragma unroll
            for (int i = 0; i < 4; ++i)
                va[i] = *reinterpret_cast<const uint4*>(
                    &vgl[(size_t)(b * SS + k0 + k4 + i) * (2 * EE) + h * DV + c8]);
#pragma unroll
            for (int j = 0; j < 8; ++j) {
                ushort_t e0 = reinterpret_cast<const ushort_t*>(&va[0])[j];
                ushort_t e1 = reinterpret_cast<const ushort_t*>(&va[1])[j];
                ushort_t e2 = reinterpret_cast<const ushort_t*>(&va[2])[j];
                ushort_t e3 = reinterpret_cast<const ushort_t*>(&va[3])[j];
                uint2 pk;
                pk.x = (unsigned)e0 | ((unsigned)e1 << 16);
                pk.y = (unsigned)e2 | ((unsigned)e3 << 16);
                *reinterpret_cast<uint2*>(&Vt[c8 + j][k4]) = pk;
            }
        }

        // ---- QK^T (S^T form), K-frags direct from global (L2) ----
        f32x4 s1[4], s2[4];
#pragma unroll
        for (int kb = 0; kb < 4; ++kb) {
            s1[kb] = fz; s2[kb] = fz;
            size_t krow = (size_t)(b * SS + k0 + kb * 16 + c) * EE + h * DH;
#pragma unroll
            for (int ks = 0; ks < 2; ++ks) {
                bf16x8 kf1 = *reinterpret_cast<const bf16x8*>(&k1b[krow + 8 * g + 32 * ks]);
                s1[kb] = __builtin_amdgcn_mfma_f32_16x16x32_bf16(kf1, qf1[ks], s1[kb], 0, 0, 0);
                bf16x8 kf2 = *reinterpret_cast<const bf16x8*>(&k2b[krow + 8 * g + 32 * ks]);
                s2[kb] = __builtin_amdgcn_mfma_f32_16x16x32_bf16(kf2, qf2[ks], s2[kb], 0, 0, 0);
            }
        }

        // ---- scale + causal mask + dual online softmax ----
        float mt1 = -1e30f, mt2 = -1e30f;
#pragma unroll
        for (int kb = 0; kb < 4; ++kb)
#pragma unroll
            for (int r = 0; r < 4; ++r) {
                float v1 = s1[kb][r] * scale;
                float v2 = s2[kb][r] * scale;
                if (diag && (kb * 16 + 4 * g + r) > (w * 16 + c)) { v1 = -1e30f; v2 = -1e30f; }
                s1[kb][r] = v1; s2[kb][r] = v2;
                mt1 = fmaxf(mt1, v1); mt2 = fmaxf(mt2, v2);
            }
        mt1 = fmaxf(mt1, __shfl_xor(mt1, 16, 64));
        mt1 = fmaxf(mt1, __shfl_xor(mt1, 32, 64));
        mt2 = fmaxf(mt2, __shfl_xor(mt2, 16, 64));
        mt2 = fmaxf(mt2, __shfl_xor(mt2, 32, 64));
        float mn1 = fmaxf(m1, mt1), mn2 = fmaxf(m2, mt2);
        float f1 = __expf(m1 - mn1), f2 = __expf(m2 - mn2);
        float rs1 = 0.f, rs2 = 0.f;
#pragma unroll
        for (int kb = 0; kb < 4; ++kb) {
            ushort_t u1[4], u2[4];
#pragma unroll
            for (int r = 0; r < 4; ++r) {
                float p1 = __expf(s1[kb][r] - mn1); rs1 += p1;
                float p2 = __expf(s2[kb][r] - mn2); rs2 += p2;
                bf16 h1 = __float2bfloat16(p1);
                bf16 h2 = __float2bfloat16(p2);
                u1[r] = *reinterpret_cast<ushort_t*>(&h1);
                u2[r] = *reinterpret_cast<ushort_t*>(&h2);
            }
            uint2 w1, w2;
            w1.x = (unsigned)u1[0] | ((unsigned)u1[1] << 16);
            w1.y = (unsigned)u1[2] | ((unsigned)u1[3] << 16);
            w2.x = (unsigned)u2[0] | ((unsigned)u2[1] << 16);
            w2.y = (unsigned)u2[2] | ((unsigned)u2[3] << 16);
            *reinterpret_cast<uint2*>(&P1s[w][c][kb * 16 + 4 * g]) = w1;
            *reinterpret_cast<uint2*>(&P2s[w][c][kb * 16 + 4 * g]) = w2;
        }
        rs1 += __shfl_xor(rs1, 16, 64); rs1 += __shfl_xor(rs1, 32, 64);
        rs2 += __shfl_xor(rs2, 16, 64); rs2 += __shfl_xor(rs2, 32, 64);
        l1 = l1 * f1 + rs1;  l2 = l2 * f2 + rs2;
        m1 = mn1;  m2 = mn2;

        // ---- rescale O accumulators (per-row factors redistributed) ----
#pragma unroll
        for (int r = 0; r < 4; ++r) {
            float f1o = __shfl(f1, 4 * g + r, 64);
            float f2o = __shfl(f2, 4 * g + r, 64);
#pragma unroll
            for (int vb = 0; vb < 8; ++vb) { acc1[vb][r] *= f1o; acc2[vb][r] *= f2o; }
        }
        __syncthreads();   // Vt + P visible to all

        // ---- PV: O += P·V for both streams ----
#pragma unroll
        for (int ks = 0; ks < 2; ++ks) {
            bf16x8 pa1 = *reinterpret_cast<const bf16x8*>(&P1s[w][c][8 * g + 32 * ks]);
            bf16x8 pa2 = *reinterpret_cast<const bf16x8*>(&P2s[w][c][8 * g + 32 * ks]);
#pragma unroll
            for (int vb = 0; vb < 8; ++vb) {
                bf16x8 vf = *reinterpret_cast<const bf16x8*>(&Vt[c + 16 * vb][8 * g + 32 * ks]);
                acc1[vb] = __builtin_amdgcn_mfma_f32_16x16x32_bf16(pa1, vf, acc1[vb], 0, 0, 0);
                acc2[vb] = __builtin_amdgcn_mfma_f32_16x16x32_bf16(pa2, vf, acc2[vb], 0, 0, 0);
            }
        }
    }

    // ---- epilogue: combine, LayerNorm(128), scale, store merged bf16 ----
    float rl1[4], rl2[4];
#pragma unroll
    for (int r = 0; r < 4; ++r) {
        rl1[r] = __builtin_amdgcn_rcpf(__shfl(l1, 4 * g + r, 64));
        rl2[r] = __builtin_amdgcn_rcpf(__shfl(l2, 4 * g + r, 64));
    }
    float sum[4] = {0.f, 0.f, 0.f, 0.f};
#pragma unroll
    for (int vb = 0; vb < 8; ++vb)
#pragma unroll
        for (int r = 0; r < 4; ++r) {
            float v = acc1[vb][r] * rl1[r] - lam * (acc2[vb][r] * rl2[r]);
            acc1[vb][r] = v;
            sum[r] += v;
        }
#pragma unroll
    for (int r = 0; r < 4; ++r) {
#pragma unroll
        for (int m = 8; m >= 1; m >>= 1) sum[r] += __shfl_xor(sum[r], m, 64);
        sum[r] *= (1.f / 128.f);   // mu
    }
    float var[4] = {0.f, 0.f, 0.f, 0.f};
#pragma unroll
    for (int vb = 0; vb < 8; ++vb)
#pragma unroll
        for (int r = 0; r < 4; ++r) {
            float d = acc1[vb][r] - sum[r];
            var[r] += d * d;
        }
#pragma unroll
    for (int r = 0; r < 4; ++r) {
#pragma unroll
        for (int m = 8; m >= 1; m >>= 1) var[r] += __shfl_xor(var[r], m, 64);
        var[r] = rsqrtf(var[r] * (1.f / 128.f) + LN_EPS) * (1.f - LAM0);
    }
#pragma unroll
    for (int vb = 0; vb < 8; ++vb)
#pragma unroll
        for (int r = 0; r < 4; ++r) {
            size_t idx = (size_t)(b * SS + q0 + w * 16 + 4 * g + r) * (2 * EE)
                       + h * DV + c + 16 * vb;
            merged[idx] = __float2bfloat16((acc1[vb][r] - sum[r]) * var[r]);
        }
}

// ---------------- launch ----------------
extern "C" void kernel_launch(void* const* d_in, const int* in_sizes, int n_in,
                              void* d_out, int out_size, void* d_ws, size_t ws_size,
                              hipStream_t stream) {
    (void)in_sizes; (void)n_in; (void)out_size; (void)ws_size;
    const float* x   = (const float*)d_in[0];
    const float* Wq1 = (const float*)d_in[1];
    const float* Wq2 = (const float*)d_in[2];
    const float* Wk1 = (const float*)d_in[3];
    const float* Wk2 = (const float*)d_in[4];
    const float* Wv  = (const float*)d_in[5];
    const float* Wo  = (const float*)d_in[6];
    const float* lq1 = (const float*)d_in[7];
    const float* lk1 = (const float*)d_in[8];
    const float* lq2 = (const float*)d_in[9];
    const float* lk2 = (const float*)d_in[10];
    float* out = (float*)d_out;

    char* ws = (char*)d_ws;
    const size_t MB = 1ull << 20;
    bf16* q1  = (bf16*)(ws);             // 4096x1024 bf16 = 8MB
    bf16* q2  = (bf16*)(ws + 8  * MB);
    bf16* k1  = (bf16*)(ws + 16 * MB);
    bf16* k2  = (bf16*)(ws + 24 * MB);
    bf16* v   = (bf16*)(ws + 32 * MB);   // 4096x2048 bf16 = 16MB
    bf16* mg  = (bf16*)(ws + 48 * MB);   // 4096x2048 bf16 = 16MB

    dim3 blk(256);
    gemm64<float, bf16><<<dim3(16, 64), blk, 0, stream>>>(x, Wq1, q1, 1024, 1024);
    gemm64<float, bf16><<<dim3(16, 64), blk, 0, stream>>>(x, Wq2, q2, 1024, 1024);
    gemm64<float, bf16><<<dim3(16, 64), blk, 0, stream>>>(x, Wk1, k1, 1024, 1024);
    gemm64<float, bf16><<<dim3(16, 64), blk, 0, stream>>>(x, Wk2, k2, 1024, 1024);
    gemm64<float, bf16><<<dim3(32, 64), blk, 0, stream>>>(x, Wv,  v,  2048, 1024);
    attn_mfma<<<dim3(NB * NH * (SS / 64)), blk, 0, stream>>>(
        q1, q2, k1, k2, v, lq1, lk1, lq2, lk2, mg);
    gemm64<bf16, float><<<dim3(16, 64), blk, 0, stream>>>(mg, Wo, out, 1024, 2048);
}

// Round 3
// 450.280 us; speedup vs baseline: 9.4889x; 3.2602x over previous
//
#include <hip/hip_runtime.h>
#include <hip/hip_bf16.h>

typedef __hip_bfloat16 bf16;
typedef __bf16 bf16x8 __attribute__((ext_vector_type(8)));
typedef float f32x4 __attribute__((ext_vector_type(4)));
typedef unsigned short ushort_t;

#define NH 16
#define NB 2
#define SS 2048
#define EE 1024
#define DH 64
#define DV 128
#define PJW 6144           // fused projection output row width
#define Q1O 0
#define Q2O 1024
#define K1O 2048
#define K2O 3072
#define VO  4096
#define LAM0 0.7778701f    // 0.8 - 0.6*exp(-0.3*11)
#define LN_EPS 1e-5f
#define PSTR 72            // padded LDS row stride (bf16 elems)

// ---- async global->LDS, 16B per lane (linear dest, lane-ordered) ----
__device__ __forceinline__ void gload_lds16(const bf16* g, bf16* l) {
    __builtin_amdgcn_global_load_lds(
        (const __attribute__((address_space(1))) void*)g,
        (__attribute__((address_space(3))) void*)l, 16, 0, 0);
}

__device__ __forceinline__ void stC(float* p, float v) { *p = v; }
__device__ __forceinline__ void stC(bf16* p, float v) { *p = __float2bfloat16(v); }

// ---------------- transpose-convert: W f32 [K][N] -> WT bf16 [noff+n][k] ----------------
__global__ __launch_bounds__(256) void transp(const float* __restrict__ W,
                                              bf16* __restrict__ WT,
                                              int K, int N, int KST, int noff) {
    __shared__ float Ts[32][33];
    int n0 = blockIdx.x * 32, k0 = blockIdx.y * 32;
    int t = threadIdx.x, tx = t & 31, ty = t >> 5;
#pragma unroll
    for (int p = 0; p < 4; ++p)
        Ts[ty + 8 * p][tx] = W[(size_t)(k0 + ty + 8 * p) * N + n0 + tx];
    __syncthreads();
#pragma unroll
    for (int p = 0; p < 4; ++p)
        WT[(size_t)(noff + n0 + ty + 8 * p) * KST + k0 + tx] =
            __float2bfloat16(Ts[tx][ty + 8 * p]);
}

// ---------------- MFMA GEMM: C[M][N] = A[M][K] @ Bt[N][K]^T ----------------
// 128x128 tile, BK=32, 256 thr = 4 waves (2x2), wave = 4x4 frags of 16x16x32.
// SPLIT: A is f32, reg-staged as hi+lo bf16 (x at ~f32 precision, 2 MFMA/frag).
// !SPLIT: A is bf16, staged via global_load_lds. B always bf16 global_load_lds.
template<bool SPLIT, typename CT>
__global__ __launch_bounds__(256) void mgemm(const void* __restrict__ Ap,
                                             const bf16* __restrict__ Bt,
                                             CT* __restrict__ C,
                                             int M, int N, int K) {
    __shared__ bf16 Ahi[128][32];
    __shared__ bf16 Alo[128][32];
    __shared__ bf16 Bs[128][32];

    const int t = threadIdx.x;
    const int w = t >> 6, l = t & 63;
    const int c = l & 15, g = l >> 4;
    const int wr = w >> 1, wc = w & 1;

    // XCD-aware swizzle (gridDim.x % 8 == 0 by construction)
    const int nwg = gridDim.x, cpx = nwg >> 3;
    const int sw = (blockIdx.x & 7) * cpx + (blockIdx.x >> 3);
    const int nbx = N >> 7;
    const int bx = sw % nbx, by = sw / nbx;
    const int row0 = by * 128, col0 = bx * 128;

    f32x4 acc[4][4];
    const f32x4 fz = {0.f, 0.f, 0.f, 0.f};
#pragma unroll
    for (int m = 0; m < 4; ++m)
#pragma unroll
        for (int n = 0; n < 4; ++n) acc[m][n] = fz;

    for (int k0 = 0; k0 < K; k0 += 32) {
        __syncthreads();   // LDS free to overwrite
        // ---- stage B tile: Bt rows col0..col0+127 ----
#pragma unroll
        for (int i = 0; i < 2; ++i) {
            int r = i * 64 + w * 16 + (l >> 2);
            gload_lds16(&Bt[(size_t)(col0 + r) * K + k0 + (l & 3) * 8],
                        &Bs[0][0] + (size_t)(i * 4 + w) * 512 + l * 8);
        }
        // ---- stage A tile ----
        if constexpr (SPLIT) {
            const float* A = (const float*)Ap;
#pragma unroll
            for (int i = 0; i < 4; ++i) {
                int r = (t >> 3) + 32 * i;
                const float4 v = *reinterpret_cast<const float4*>(
                    &A[(size_t)(row0 + r) * K + k0 + (t & 7) * 4]);
                float f[4] = {v.x, v.y, v.z, v.w};
                ushort_t hi[4], lo[4];
#pragma unroll
                for (int j = 0; j < 4; ++j) {
                    bf16 h = __float2bfloat16(f[j]);
                    bf16 e = __float2bfloat16(f[j] - __bfloat162float(h));
                    hi[j] = *reinterpret_cast<ushort_t*>(&h);
                    lo[j] = *reinterpret_cast<ushort_t*>(&e);
                }
                uint2 hp, lp;
                hp.x = (unsigned)hi[0] | ((unsigned)hi[1] << 16);
                hp.y = (unsigned)hi[2] | ((unsigned)hi[3] << 16);
                lp.x = (unsigned)lo[0] | ((unsigned)lo[1] << 16);
                lp.y = (unsigned)lo[2] | ((unsigned)lo[3] << 16);
                *reinterpret_cast<uint2*>(&Ahi[r][(t & 7) * 4]) = hp;
                *reinterpret_cast<uint2*>(&Alo[r][(t & 7) * 4]) = lp;
            }
        } else {
            const bf16* A = (const bf16*)Ap;
#pragma unroll
            for (int i = 0; i < 2; ++i) {
                int r = i * 64 + w * 16 + (l >> 2);
                gload_lds16(&A[(size_t)(row0 + r) * K + k0 + (l & 3) * 8],
                            &Ahi[0][0] + (size_t)(i * 4 + w) * 512 + l * 8);
            }
        }
        __syncthreads();   // staged (barrier drains vmcnt/lgkmcnt)

        // ---- fragments + MFMA ----
        bf16x8 af[4], bfr[4];
#pragma unroll
        for (int m = 0; m < 4; ++m)
            af[m] = *reinterpret_cast<const bf16x8*>(&Ahi[wr * 64 + m * 16 + c][g * 8]);
#pragma unroll
        for (int n = 0; n < 4; ++n)
            bfr[n] = *reinterpret_cast<const bf16x8*>(&Bs[wc * 64 + n * 16 + c][g * 8]);
#pragma unroll
        for (int m = 0; m < 4; ++m)
#pragma unroll
            for (int n = 0; n < 4; ++n)
                acc[m][n] = __builtin_amdgcn_mfma_f32_16x16x32_bf16(af[m], bfr[n], acc[m][n], 0, 0, 0);
        if constexpr (SPLIT) {
            bf16x8 al[4];
#pragma unroll
            for (int m = 0; m < 4; ++m)
                al[m] = *reinterpret_cast<const bf16x8*>(&Alo[wr * 64 + m * 16 + c][g * 8]);
#pragma unroll
            for (int m = 0; m < 4; ++m)
#pragma unroll
                for (int n = 0; n < 4; ++n)
                    acc[m][n] = __builtin_amdgcn_mfma_f32_16x16x32_bf16(al[m], bfr[n], acc[m][n], 0, 0, 0);
        }
    }

    // ---- epilogue: C/D layout col=lane&15, row=(lane>>4)*4+r ----
#pragma unroll
    for (int m = 0; m < 4; ++m)
#pragma unroll
        for (int n = 0; n < 4; ++n)
#pragma unroll
            for (int r = 0; r < 4; ++r) {
                int row = row0 + wr * 64 + m * 16 + g * 4 + r;
                int col = col0 + wc * 64 + n * 16 + c;
                stC(&C[(size_t)row * N + col], acc[m][n][r]);
            }
}

// ---------------- MFMA differential flash attention + LayerNorm ----------------
// (structure verified in R2; only change: reads q/k/v from fused Cproj, stride PJW)
__global__ __launch_bounds__(256) void attn_mfma(
        const bf16* __restrict__ cp,
        const float* __restrict__ lq1, const float* __restrict__ lk1,
        const float* __restrict__ lq2, const float* __restrict__ lk2,
        bf16* __restrict__ merged) {
    __shared__ ushort_t Vt[DV][PSTR];
    __shared__ ushort_t P1s[4][16][PSTR];
    __shared__ ushort_t P2s[4][16][PSTR];

    const int t = threadIdx.x;
    const int w = t >> 6, l = t & 63;
    const int g = l >> 4, c = l & 15;

    const int bid = blockIdx.x;
    const int qt  = (SS / 64 - 1) - (bid >> 5);
    const int bh  = bid & 31;
    const int h   = bh & (NH - 1), b = bh >> 4;
    const int q0  = qt * 64;

    float lam;
    {
        float s1 = lq1[h * DH + l] * lk1[h * DH + l];
        float s2 = lq2[h * DH + l] * lk2[h * DH + l];
#pragma unroll
        for (int m = 32; m >= 1; m >>= 1) {
            s1 += __shfl_xor(s1, m, 64);
            s2 += __shfl_xor(s2, m, 64);
        }
        lam = __expf(s1) - __expf(s2) + LAM0;
    }

    bf16x8 qf1[2], qf2[2];
    {
        size_t qrow = (size_t)(b * SS + q0 + w * 16 + c) * PJW + h * DH;
#pragma unroll
        for (int ks = 0; ks < 2; ++ks) {
            qf1[ks] = *reinterpret_cast<const bf16x8*>(&cp[qrow + Q1O + 8 * g + 32 * ks]);
            qf2[ks] = *reinterpret_cast<const bf16x8*>(&cp[qrow + Q2O + 8 * g + 32 * ks]);
        }
    }

    f32x4 acc1[8], acc2[8];
    const f32x4 fz = {0.f, 0.f, 0.f, 0.f};
#pragma unroll
    for (int i = 0; i < 8; ++i) { acc1[i] = fz; acc2[i] = fz; }
    float m1 = -1e30f, m2 = -1e30f, l1 = 0.f, l2 = 0.f;
    const float scale = 0.125f;

    for (int kt = 0; kt <= qt; ++kt) {
        const int k0 = kt * 64;
        const bool diag = (kt == qt);
        __syncthreads();

        {   // stage Vt (transposed V tile)
            const int k4 = (t & 15) * 4;
            const int c8 = (t >> 4) * 8;
            uint4 va[4];
#pragma unroll
            for (int i = 0; i < 4; ++i)
                va[i] = *reinterpret_cast<const uint4*>(
                    &cp[(size_t)(b * SS + k0 + k4 + i) * PJW + VO + h * DV + c8]);
#pragma unroll
            for (int j = 0; j < 8; ++j) {
                ushort_t e0 = reinterpret_cast<const ushort_t*>(&va[0])[j];
                ushort_t e1 = reinterpret_cast<const ushort_t*>(&va[1])[j];
                ushort_t e2 = reinterpret_cast<const ushort_t*>(&va[2])[j];
                ushort_t e3 = reinterpret_cast<const ushort_t*>(&va[3])[j];
                uint2 pk;
                pk.x = (unsigned)e0 | ((unsigned)e1 << 16);
                pk.y = (unsigned)e2 | ((unsigned)e3 << 16);
                *reinterpret_cast<uint2*>(&Vt[c8 + j][k4]) = pk;
            }
        }

        // QK^T (S^T form), K-frags from global (L2/L3)
        f32x4 s1[4], s2[4];
#pragma unroll
        for (int kb = 0; kb < 4; ++kb) {
            s1[kb] = fz; s2[kb] = fz;
            size_t krow = (size_t)(b * SS + k0 + kb * 16 + c) * PJW + h * DH;
#pragma unroll
            for (int ks = 0; ks < 2; ++ks) {
                bf16x8 kf1 = *reinterpret_cast<const bf16x8*>(&cp[krow + K1O + 8 * g + 32 * ks]);
                s1[kb] = __builtin_amdgcn_mfma_f32_16x16x32_bf16(kf1, qf1[ks], s1[kb], 0, 0, 0);
                bf16x8 kf2 = *reinterpret_cast<const bf16x8*>(&cp[krow + K2O + 8 * g + 32 * ks]);
                s2[kb] = __builtin_amdgcn_mfma_f32_16x16x32_bf16(kf2, qf2[ks], s2[kb], 0, 0, 0);
            }
        }

        float mt1 = -1e30f, mt2 = -1e30f;
#pragma unroll
        for (int kb = 0; kb < 4; ++kb)
#pragma unroll
            for (int r = 0; r < 4; ++r) {
                float v1 = s1[kb][r] * scale;
                float v2 = s2[kb][r] * scale;
                if (diag && (kb * 16 + 4 * g + r) > (w * 16 + c)) { v1 = -1e30f; v2 = -1e30f; }
                s1[kb][r] = v1; s2[kb][r] = v2;
                mt1 = fmaxf(mt1, v1); mt2 = fmaxf(mt2, v2);
            }
        mt1 = fmaxf(mt1, __shfl_xor(mt1, 16, 64));
        mt1 = fmaxf(mt1, __shfl_xor(mt1, 32, 64));
        mt2 = fmaxf(mt2, __shfl_xor(mt2, 16, 64));
        mt2 = fmaxf(mt2, __shfl_xor(mt2, 32, 64));
        float mn1 = fmaxf(m1, mt1), mn2 = fmaxf(m2, mt2);
        float f1 = __expf(m1 - mn1), f2 = __expf(m2 - mn2);
        float rs1 = 0.f, rs2 = 0.f;
#pragma unroll
        for (int kb = 0; kb < 4; ++kb) {
            ushort_t u1[4], u2[4];
#pragma unroll
            for (int r = 0; r < 4; ++r) {
                float p1 = __expf(s1[kb][r] - mn1); rs1 += p1;
                float p2 = __expf(s2[kb][r] - mn2); rs2 += p2;
                bf16 h1 = __float2bfloat16(p1);
                bf16 h2 = __float2bfloat16(p2);
                u1[r] = *reinterpret_cast<ushort_t*>(&h1);
                u2[r] = *reinterpret_cast<ushort_t*>(&h2);
            }
            uint2 w1, w2;
            w1.x = (unsigned)u1[0] | ((unsigned)u1[1] << 16);
            w1.y = (unsigned)u1[2] | ((unsigned)u1[3] << 16);
            w2.x = (unsigned)u2[0] | ((unsigned)u2[1] << 16);
            w2.y = (unsigned)u2[2] | ((unsigned)u2[3] << 16);
            *reinterpret_cast<uint2*>(&P1s[w][c][kb * 16 + 4 * g]) = w1;
            *reinterpret_cast<uint2*>(&P2s[w][c][kb * 16 + 4 * g]) = w2;
        }
        rs1 += __shfl_xor(rs1, 16, 64); rs1 += __shfl_xor(rs1, 32, 64);
        rs2 += __shfl_xor(rs2, 16, 64); rs2 += __shfl_xor(rs2, 32, 64);
        l1 = l1 * f1 + rs1;  l2 = l2 * f2 + rs2;
        m1 = mn1;  m2 = mn2;

#pragma unroll
        for (int r = 0; r < 4; ++r) {
            float f1o = __shfl(f1, 4 * g + r, 64);
            float f2o = __shfl(f2, 4 * g + r, 64);
#pragma unroll
            for (int vb = 0; vb < 8; ++vb) { acc1[vb][r] *= f1o; acc2[vb][r] *= f2o; }
        }
        __syncthreads();

#pragma unroll
        for (int ks = 0; ks < 2; ++ks) {
            bf16x8 pa1 = *reinterpret_cast<const bf16x8*>(&P1s[w][c][8 * g + 32 * ks]);
            bf16x8 pa2 = *reinterpret_cast<const bf16x8*>(&P2s[w][c][8 * g + 32 * ks]);
#pragma unroll
            for (int vb = 0; vb < 8; ++vb) {
                bf16x8 vf = *reinterpret_cast<const bf16x8*>(&Vt[c + 16 * vb][8 * g + 32 * ks]);
                acc1[vb] = __builtin_amdgcn_mfma_f32_16x16x32_bf16(pa1, vf, acc1[vb], 0, 0, 0);
                acc2[vb] = __builtin_amdgcn_mfma_f32_16x16x32_bf16(pa2, vf, acc2[vb], 0, 0, 0);
            }
        }
    }

    float rl1[4], rl2[4];
#pragma unroll
    for (int r = 0; r < 4; ++r) {
        rl1[r] = __builtin_amdgcn_rcpf(__shfl(l1, 4 * g + r, 64));
        rl2[r] = __builtin_amdgcn_rcpf(__shfl(l2, 4 * g + r, 64));
    }
    float sum[4] = {0.f, 0.f, 0.f, 0.f};
#pragma unroll
    for (int vb = 0; vb < 8; ++vb)
#pragma unroll
        for (int r = 0; r < 4; ++r) {
            float v = acc1[vb][r] * rl1[r] - lam * (acc2[vb][r] * rl2[r]);
            acc1[vb][r] = v;
            sum[r] += v;
        }
#pragma unroll
    for (int r = 0; r < 4; ++r) {
#pragma unroll
        for (int m = 8; m >= 1; m >>= 1) sum[r] += __shfl_xor(sum[r], m, 64);
        sum[r] *= (1.f / 128.f);
    }
    float var[4] = {0.f, 0.f, 0.f, 0.f};
#pragma unroll
    for (int vb = 0; vb < 8; ++vb)
#pragma unroll
        for (int r = 0; r < 4; ++r) {
            float d = acc1[vb][r] - sum[r];
            var[r] += d * d;
        }
#pragma unroll
    for (int r = 0; r < 4; ++r) {
#pragma unroll
        for (int m = 8; m >= 1; m >>= 1) var[r] += __shfl_xor(var[r], m, 64);
        var[r] = rsqrtf(var[r] * (1.f / 128.f) + LN_EPS) * (1.f - LAM0);
    }
#pragma unroll
    for (int vb = 0; vb < 8; ++vb)
#pragma unroll
        for (int r = 0; r < 4; ++r) {
            size_t idx = (size_t)(b * SS + q0 + w * 16 + 4 * g + r) * (2 * EE)
                       + h * DV + c + 16 * vb;
            merged[idx] = __float2bfloat16((acc1[vb][r] - sum[r]) * var[r]);
        }
}

// ---------------- launch ----------------
extern "C" void kernel_launch(void* const* d_in, const int* in_sizes, int n_in,
                              void* d_out, int out_size, void* d_ws, size_t ws_size,
                              hipStream_t stream) {
    (void)in_sizes; (void)n_in; (void)out_size; (void)ws_size;
    const float* x   = (const float*)d_in[0];
    const float* Wq1 = (const float*)d_in[1];
    const float* Wq2 = (const float*)d_in[2];
    const float* Wk1 = (const float*)d_in[3];
    const float* Wk2 = (const float*)d_in[4];
    const float* Wv  = (const float*)d_in[5];
    const float* Wo  = (const float*)d_in[6];
    const float* lq1 = (const float*)d_in[7];
    const float* lk1 = (const float*)d_in[8];
    const float* lq2 = (const float*)d_in[9];
    const float* lk2 = (const float*)d_in[10];
    float* out = (float*)d_out;

    // ws lifetimes (64 MB total):
    //   WcatT [0,12M)   : weight transposes -> end of proj GEMM
    //   Cproj [16M,64M) : proj GEMM -> end of attention
    //   mg    [0,16M)   : attention -> final GEMM   (over dead WcatT)
    //   WoT   [16M,20M) : after attention -> final  (over dead Cproj)
    char* ws = (char*)d_ws;
    const size_t MB = 1ull << 20;
    bf16* wcT = (bf16*)(ws);
    bf16* cpj = (bf16*)(ws + 16 * MB);
    bf16* mg  = (bf16*)(ws);
    bf16* woT = (bf16*)(ws + 16 * MB);

    dim3 blk(256);
    // weight transposes into WcatT rows [0,6144)
    transp<<<dim3(32, 32), blk, 0, stream>>>(Wq1, wcT, 1024, 1024, 1024, Q1O);
    transp<<<dim3(32, 32), blk, 0, stream>>>(Wq2, wcT, 1024, 1024, 1024, Q2O);
    transp<<<dim3(32, 32), blk, 0, stream>>>(Wk1, wcT, 1024, 1024, 1024, K1O);
    transp<<<dim3(32, 32), blk, 0, stream>>>(Wk2, wcT, 1024, 1024, 1024, K2O);
    transp<<<dim3(64, 32), blk, 0, stream>>>(Wv,  wcT, 1024, 2048, 1024, VO);
    // fused projection GEMM: Cproj = x @ [Wq1|Wq2|Wk1|Wk2|Wv]  (hi/lo split A)
    mgemm<true, bf16><<<dim3((6144 / 128) * (4096 / 128)), blk, 0, stream>>>(
        x, wcT, cpj, 4096, 6144, 1024);
    // differential attention + LN -> mg
    attn_mfma<<<dim3(NB * NH * (SS / 64)), blk, 0, stream>>>(
        cpj, lq1, lk1, lq2, lk2, mg);
    // Wo transpose (Cproj now dead), then out = mg @ Wo
    transp<<<dim3(32, 64), blk, 0, stream>>>(Wo, woT, 2048, 1024, 2048, 0);
    mgemm<false, float><<<dim3((1024 / 128) * (4096 / 128)), blk, 0, stream>>>(
        mg, woT, out, 4096, 1024, 2048);
}

// Round 5
// 338.975 us; speedup vs baseline: 12.6047x; 1.3284x over previous
//
#include <hip/hip_runtime.h>
#include <hip/hip_bf16.h>

typedef __hip_bfloat16 bf16;
typedef __bf16 bf16x8 __attribute__((ext_vector_type(8)));
typedef float f32x4 __attribute__((ext_vector_type(4)));
typedef unsigned short ushort_t;

#define NH 16
#define NB 2
#define SS 2048
#define EE 1024
#define DH 64
#define DV 128
#define PJW 6144           // fused projection output row width
#define Q1O 0
#define Q2O 1024
#define K1O 2048
#define K2O 3072
#define VO  4096
#define LAM0 0.7778701f    // 0.8 - 0.6*exp(-0.3*11)
#define LN_EPS 1e-5f
#define PSTR 72            // padded LDS row stride (bf16 elems)

// ---- async global->LDS, 16B per lane (linear dest, lane-ordered) ----
__device__ __forceinline__ void gload_lds16(const bf16* g, bf16* l) {
    __builtin_amdgcn_global_load_lds(
        (const __attribute__((address_space(1))) void*)g,
        (__attribute__((address_space(3))) void*)l, 16, 0, 0);
}

__device__ __forceinline__ void stC(float* p, float v) { *p = v; }
__device__ __forceinline__ void stC(bf16* p, float v) { *p = __float2bfloat16(v); }

// ---------------- transpose-convert: W f32 [K][N] -> WT bf16 [noff+n][k] ----------------
__global__ __launch_bounds__(256) void transp(const float* __restrict__ W,
                                              bf16* __restrict__ WT,
                                              int K, int N, int KST, int noff) {
    __shared__ float Ts[32][33];
    int n0 = blockIdx.x * 32, k0 = blockIdx.y * 32;
    int t = threadIdx.x, tx = t & 31, ty = t >> 5;
#pragma unroll
    for (int p = 0; p < 4; ++p)
        Ts[ty + 8 * p][tx] = W[(size_t)(k0 + ty + 8 * p) * N + n0 + tx];
    __syncthreads();
#pragma unroll
    for (int p = 0; p < 4; ++p)
        WT[(size_t)(noff + n0 + ty + 8 * p) * KST + k0 + tx] =
            __float2bfloat16(Ts[tx][ty + 8 * p]);
}

// ---------------- MFMA GEMM (unchanged, verified R3) ----------------
template<bool SPLIT, typename CT>
__global__ __launch_bounds__(256) void mgemm(const void* __restrict__ Ap,
                                             const bf16* __restrict__ Bt,
                                             CT* __restrict__ C,
                                             int M, int N, int K) {
    __shared__ bf16 Ahi[128][32];
    __shared__ bf16 Alo[128][32];
    __shared__ bf16 Bs[128][32];

    const int t = threadIdx.x;
    const int w = t >> 6, l = t & 63;
    const int c = l & 15, g = l >> 4;
    const int wr = w >> 1, wc = w & 1;

    const int nwg = gridDim.x, cpx = nwg >> 3;
    const int sw = (blockIdx.x & 7) * cpx + (blockIdx.x >> 3);
    const int nbx = N >> 7;
    const int bx = sw % nbx, by = sw / nbx;
    const int row0 = by * 128, col0 = bx * 128;

    f32x4 acc[4][4];
    const f32x4 fz = {0.f, 0.f, 0.f, 0.f};
#pragma unroll
    for (int m = 0; m < 4; ++m)
#pragma unroll
        for (int n = 0; n < 4; ++n) acc[m][n] = fz;

    for (int k0 = 0; k0 < K; k0 += 32) {
        __syncthreads();
#pragma unroll
        for (int i = 0; i < 2; ++i) {
            int r = i * 64 + w * 16 + (l >> 2);
            gload_lds16(&Bt[(size_t)(col0 + r) * K + k0 + (l & 3) * 8],
                        &Bs[0][0] + (size_t)(i * 4 + w) * 512 + l * 8);
        }
        if constexpr (SPLIT) {
            const float* A = (const float*)Ap;
#pragma unroll
            for (int i = 0; i < 4; ++i) {
                int r = (t >> 3) + 32 * i;
                const float4 v = *reinterpret_cast<const float4*>(
                    &A[(size_t)(row0 + r) * K + k0 + (t & 7) * 4]);
                float f[4] = {v.x, v.y, v.z, v.w};
                ushort_t hi[4], lo[4];
#pragma unroll
                for (int j = 0; j < 4; ++j) {
                    bf16 h = __float2bfloat16(f[j]);
                    bf16 e = __float2bfloat16(f[j] - __bfloat162float(h));
                    hi[j] = *reinterpret_cast<ushort_t*>(&h);
                    lo[j] = *reinterpret_cast<ushort_t*>(&e);
                }
                uint2 hp, lp;
                hp.x = (unsigned)hi[0] | ((unsigned)hi[1] << 16);
                hp.y = (unsigned)hi[2] | ((unsigned)hi[3] << 16);
                lp.x = (unsigned)lo[0] | ((unsigned)lo[1] << 16);
                lp.y = (unsigned)lo[2] | ((unsigned)lo[3] << 16);
                *reinterpret_cast<uint2*>(&Ahi[r][(t & 7) * 4]) = hp;
                *reinterpret_cast<uint2*>(&Alo[r][(t & 7) * 4]) = lp;
            }
        } else {
            const bf16* A = (const bf16*)Ap;
#pragma unroll
            for (int i = 0; i < 2; ++i) {
                int r = i * 64 + w * 16 + (l >> 2);
                gload_lds16(&A[(size_t)(row0 + r) * K + k0 + (l & 3) * 8],
                            &Ahi[0][0] + (size_t)(i * 4 + w) * 512 + l * 8);
            }
        }
        __syncthreads();

        bf16x8 af[4], bfr[4];
#pragma unroll
        for (int m = 0; m < 4; ++m)
            af[m] = *reinterpret_cast<const bf16x8*>(&Ahi[wr * 64 + m * 16 + c][g * 8]);
#pragma unroll
        for (int n = 0; n < 4; ++n)
            bfr[n] = *reinterpret_cast<const bf16x8*>(&Bs[wc * 64 + n * 16 + c][g * 8]);
#pragma unroll
        for (int m = 0; m < 4; ++m)
#pragma unroll
            for (int n = 0; n < 4; ++n)
                acc[m][n] = __builtin_amdgcn_mfma_f32_16x16x32_bf16(af[m], bfr[n], acc[m][n], 0, 0, 0);
        if constexpr (SPLIT) {
            bf16x8 al[4];
#pragma unroll
            for (int m = 0; m < 4; ++m)
                al[m] = *reinterpret_cast<const bf16x8*>(&Alo[wr * 64 + m * 16 + c][g * 8]);
#pragma unroll
            for (int m = 0; m < 4; ++m)
#pragma unroll
                for (int n = 0; n < 4; ++n)
                    acc[m][n] = __builtin_amdgcn_mfma_f32_16x16x32_bf16(al[m], bfr[n], acc[m][n], 0, 0, 0);
        }
    }

#pragma unroll
    for (int m = 0; m < 4; ++m)
#pragma unroll
        for (int n = 0; n < 4; ++n)
#pragma unroll
            for (int r = 0; r < 4; ++r) {
                int row = row0 + wr * 64 + m * 16 + g * 4 + r;
                int col = col0 + wc * 64 + n * 16 + c;
                stC(&C[(size_t)row * N + col], acc[m][n][r]);
            }
}

// ---------------- MFMA differential flash attention + LayerNorm, pipelined ----------------
// K1/K2 double-buffered in LDS via global_load_lds, XOR-swizzled source (prefetch 1 tile).
// V prefetched to regs 1 tile ahead; Vt transpose-packed at tile start.
// Barrier B is raw s_barrier + lgkmcnt(0) only -> prefetches stay in flight across it.
__global__ __launch_bounds__(256) void attn_mfma(
        const bf16* __restrict__ cp,
        const float* __restrict__ lq1, const float* __restrict__ lk1,
        const float* __restrict__ lq2, const float* __restrict__ lk2,
        bf16* __restrict__ merged) {
    __shared__ ushort_t K1s[2][64][64];
    __shared__ ushort_t K2s[2][64][64];
    __shared__ ushort_t Vt[DV][PSTR];
    __shared__ ushort_t P1s[4][16][PSTR];
    __shared__ ushort_t P2s[4][16][PSTR];

    const int t = threadIdx.x;
    const int w = t >> 6, l = t & 63;
    const int g = l >> 4, c = l & 15;

    const int bid = blockIdx.x;
    const int qt  = (SS / 64 - 1) - (bid >> 5);
    const int bh  = bid & 31;
    const int h   = bh & (NH - 1), b = bh >> 4;
    const int q0  = qt * 64;

    float lam;
    {
        float s1 = lq1[h * DH + l] * lk1[h * DH + l];
        float s2 = lq2[h * DH + l] * lk2[h * DH + l];
#pragma unroll
        for (int m = 32; m >= 1; m >>= 1) {
            s1 += __shfl_xor(s1, m, 64);
            s2 += __shfl_xor(s2, m, 64);
        }
        lam = __expf(s1) - __expf(s2) + LAM0;
    }

    bf16x8 qf1[2], qf2[2];
    {
        size_t qrow = (size_t)(b * SS + q0 + w * 16 + c) * PJW + h * DH;
#pragma unroll
        for (int ks = 0; ks < 2; ++ks) {
            qf1[ks] = *reinterpret_cast<const bf16x8*>(&cp[qrow + Q1O + 8 * g + 32 * ks]);
            qf2[ks] = *reinterpret_cast<const bf16x8*>(&cp[qrow + Q2O + 8 * g + 32 * ks]);
        }
    }

    // --- staging helpers ---
    // K tiles: LDS [64][64] with 16B-unit XOR swizzle (unit j stores global unit j^(row&7)).
    auto stageK = [&](int k0, int buf) {
#pragma unroll
        for (int i = 0; i < 2; ++i) {
            int u = i * 256 + t;              // 16B unit index in tile
            int row = u >> 3, j = u & 7;
            int jj = j ^ (row & 7);
            size_t gb = (size_t)(b * SS + k0 + row) * PJW + h * DH + jj * 8;
            gload_lds16(&cp[gb + K1O], (bf16*)&K1s[buf][0][0] + u * 8);
            gload_lds16(&cp[gb + K2O], (bf16*)&K2s[buf][0][0] + u * 8);
        }
    };
    uint4 va[4];
    const int vk4 = (t & 15) * 4, vc8 = (t >> 4) * 8;
    auto loadV = [&](int k0) {
#pragma unroll
        for (int i = 0; i < 4; ++i)
            va[i] = *reinterpret_cast<const uint4*>(
                &cp[(size_t)(b * SS + k0 + vk4 + i) * PJW + VO + h * DV + vc8]);
    };

    f32x4 acc1[8], acc2[8];
    const f32x4 fz = {0.f, 0.f, 0.f, 0.f};
#pragma unroll
    for (int i = 0; i < 8; ++i) { acc1[i] = fz; acc2[i] = fz; }
    float m1 = -1e30f, m2 = -1e30f, l1 = 0.f, l2 = 0.f;
    const float scale = 0.125f;

    // prologue: prefetch tile 0
    stageK(0, 0);
    loadV(0);

    for (int kt = 0; kt <= qt; ++kt) {
        const int k0 = kt * 64;
        const int cur = kt & 1;
        const bool diag = (kt == qt);

        // barrier A: drains vmcnt (K[cur] DMA landed, va regs ready); prev PV done.
        __syncthreads();

        // issue next tile's K DMA first (maximum overlap window)
        if (kt < qt) stageK(k0 + 64, cur ^ 1);

        // Vt write from prefetched regs (transpose-pack)
#pragma unroll
        for (int j = 0; j < 8; ++j) {
            ushort_t e0 = reinterpret_cast<const ushort_t*>(&va[0])[j];
            ushort_t e1 = reinterpret_cast<const ushort_t*>(&va[1])[j];
            ushort_t e2 = reinterpret_cast<const ushort_t*>(&va[2])[j];
            ushort_t e3 = reinterpret_cast<const ushort_t*>(&va[3])[j];
            uint2 pk;
            pk.x = (unsigned)e0 | ((unsigned)e1 << 16);
            pk.y = (unsigned)e2 | ((unsigned)e3 << 16);
            *reinterpret_cast<uint2*>(&Vt[vc8 + j][vk4]) = pk;
        }
        // issue next tile's V loads (va regs now free)
        if (kt < qt) loadV(k0 + 64);

        // ---- QK^T from LDS (swizzled ds_read_b128) ----
        f32x4 s1[4], s2[4];
        __builtin_amdgcn_s_setprio(1);
#pragma unroll
        for (int kb = 0; kb < 4; ++kb) {
            s1[kb] = fz; s2[kb] = fz;
            const int row = kb * 16 + c;
#pragma unroll
            for (int ks = 0; ks < 2; ++ks) {
                const int un = ((g + 4 * ks) ^ (row & 7)) * 8;
                bf16x8 kf1 = *reinterpret_cast<const bf16x8*>(&K1s[cur][row][un]);
                s1[kb] = __builtin_amdgcn_mfma_f32_16x16x32_bf16(kf1, qf1[ks], s1[kb], 0, 0, 0);
                bf16x8 kf2 = *reinterpret_cast<const bf16x8*>(&K2s[cur][row][un]);
                s2[kb] = __builtin_amdgcn_mfma_f32_16x16x32_bf16(kf2, qf2[ks], s2[kb], 0, 0, 0);
            }
        }
        __builtin_amdgcn_s_setprio(0);

        // ---- scale + causal mask + dual online softmax (defer-max) ----
        float mt1 = -1e30f, mt2 = -1e30f;
#pragma unroll
        for (int kb = 0; kb < 4; ++kb)
#pragma unroll
            for (int r = 0; r < 4; ++r) {
                float v1 = s1[kb][r] * scale;
                float v2 = s2[kb][r] * scale;
                if (diag && (kb * 16 + 4 * g + r) > (w * 16 + c)) { v1 = -1e30f; v2 = -1e30f; }
                s1[kb][r] = v1; s2[kb][r] = v2;
                mt1 = fmaxf(mt1, v1); mt2 = fmaxf(mt2, v2);
            }
        mt1 = fmaxf(mt1, __shfl_xor(mt1, 16, 64));
        mt1 = fmaxf(mt1, __shfl_xor(mt1, 32, 64));
        mt2 = fmaxf(mt2, __shfl_xor(mt2, 16, 64));
        mt2 = fmaxf(mt2, __shfl_xor(mt2, 32, 64));

        float f1 = 1.f, f2 = 1.f;
        if (!__all((mt1 - m1 <= 8.f) && (mt2 - m2 <= 8.f))) {
            float mn1 = fmaxf(m1, mt1), mn2 = fmaxf(m2, mt2);
            f1 = __expf(m1 - mn1); f2 = __expf(m2 - mn2);
            m1 = mn1; m2 = mn2;
#pragma unroll
            for (int r = 0; r < 4; ++r) {
                float f1o = __shfl(f1, 4 * g + r, 64);
                float f2o = __shfl(f2, 4 * g + r, 64);
#pragma unroll
                for (int vb = 0; vb < 8; ++vb) { acc1[vb][r] *= f1o; acc2[vb][r] *= f2o; }
            }
        }

        float rs1 = 0.f, rs2 = 0.f;
#pragma unroll
        for (int kb = 0; kb < 4; ++kb) {
            ushort_t u1[4], u2[4];
#pragma unroll
            for (int r = 0; r < 4; ++r) {
                float p1 = __expf(s1[kb][r] - m1); rs1 += p1;
                float p2 = __expf(s2[kb][r] - m2); rs2 += p2;
                bf16 h1 = __float2bfloat16(p1);
                bf16 h2 = __float2bfloat16(p2);
                u1[r] = *reinterpret_cast<ushort_t*>(&h1);
                u2[r] = *reinterpret_cast<ushort_t*>(&h2);
            }
            uint2 w1, w2;
            w1.x = (unsigned)u1[0] | ((unsigned)u1[1] << 16);
            w1.y = (unsigned)u1[2] | ((unsigned)u1[3] << 16);
            w2.x = (unsigned)u2[0] | ((unsigned)u2[1] << 16);
            w2.y = (unsigned)u2[2] | ((unsigned)u2[3] << 16);
            *reinterpret_cast<uint2*>(&P1s[w][c][kb * 16 + 4 * g]) = w1;
            *reinterpret_cast<uint2*>(&P2s[w][c][kb * 16 + 4 * g]) = w2;
        }
        rs1 += __shfl_xor(rs1, 16, 64); rs1 += __shfl_xor(rs1, 32, 64);
        rs2 += __shfl_xor(rs2, 16, 64); rs2 += __shfl_xor(rs2, 32, 64);
        l1 = l1 * f1 + rs1;  l2 = l2 * f2 + rs2;

        // barrier B: Vt + P visible; NO vmcnt drain (prefetches stay in flight)
        asm volatile("s_waitcnt lgkmcnt(0)" ::: "memory");
        __builtin_amdgcn_sched_barrier(0);
        __builtin_amdgcn_s_barrier();
        __builtin_amdgcn_sched_barrier(0);

        // ---- PV ----
        __builtin_amdgcn_s_setprio(1);
#pragma unroll
        for (int ks = 0; ks < 2; ++ks) {
            bf16x8 pa1 = *reinterpret_cast<const bf16x8*>(&P1s[w][c][8 * g + 32 * ks]);
            bf16x8 pa2 = *reinterpret_cast<const bf16x8*>(&P2s[w][c][8 * g + 32 * ks]);
#pragma unroll
            for (int vb = 0; vb < 8; ++vb) {
                bf16x8 vf = *reinterpret_cast<const bf16x8*>(&Vt[c + 16 * vb][8 * g + 32 * ks]);
                acc1[vb] = __builtin_amdgcn_mfma_f32_16x16x32_bf16(pa1, vf, acc1[vb], 0, 0, 0);
                acc2[vb] = __builtin_amdgcn_mfma_f32_16x16x32_bf16(pa2, vf, acc2[vb], 0, 0, 0);
            }
        }
        __builtin_amdgcn_s_setprio(0);
    }

    // ---- epilogue: combine, LayerNorm(128), scale, store merged bf16 ----
    float rl1[4], rl2[4];
#pragma unroll
    for (int r = 0; r < 4; ++r) {
        rl1[r] = __builtin_amdgcn_rcpf(__shfl(l1, 4 * g + r, 64));
        rl2[r] = __builtin_amdgcn_rcpf(__shfl(l2, 4 * g + r, 64));
    }
    float sum[4] = {0.f, 0.f, 0.f, 0.f};
#pragma unroll
    for (int vb = 0; vb < 8; ++vb)
#pragma unroll
        for (int r = 0; r < 4; ++r) {
            float v = acc1[vb][r] * rl1[r] - lam * (acc2[vb][r] * rl2[r]);
            acc1[vb][r] = v;
            sum[r] += v;
        }
#pragma unroll
    for (int r = 0; r < 4; ++r) {
#pragma unroll
        for (int m = 8; m >= 1; m >>= 1) sum[r] += __shfl_xor(sum[r], m, 64);
        sum[r] *= (1.f / 128.f);
    }
    float var[4] = {0.f, 0.f, 0.f, 0.f};
#pragma unroll
    for (int vb = 0; vb < 8; ++vb)
#pragma unroll
        for (int r = 0; r < 4; ++r) {
            float d = acc1[vb][r] - sum[r];
            var[r] += d * d;
        }
#pragma unroll
    for (int r = 0; r < 4; ++r) {
#pragma unroll
        for (int m = 8; m >= 1; m >>= 1) var[r] += __shfl_xor(var[r], m, 64);
        var[r] = rsqrtf(var[r] * (1.f / 128.f) + LN_EPS) * (1.f - LAM0);
    }
#pragma unroll
    for (int vb = 0; vb < 8; ++vb)
#pragma unroll
        for (int r = 0; r < 4; ++r) {
            size_t idx = (size_t)(b * SS + q0 + w * 16 + 4 * g + r) * (2 * EE)
                       + h * DV + c + 16 * vb;
            merged[idx] = __float2bfloat16((acc1[vb][r] - sum[r]) * var[r]);
        }
}

// ---------------- launch ----------------
extern "C" void kernel_launch(void* const* d_in, const int* in_sizes, int n_in,
                              void* d_out, int out_size, void* d_ws, size_t ws_size,
                              hipStream_t stream) {
    (void)in_sizes; (void)n_in; (void)out_size; (void)ws_size;
    const float* x   = (const float*)d_in[0];
    const float* Wq1 = (const float*)d_in[1];
    const float* Wq2 = (const float*)d_in[2];
    const float* Wk1 = (const float*)d_in[3];
    const float* Wk2 = (const float*)d_in[4];
    const float* Wv  = (const float*)d_in[5];
    const float* Wo  = (const float*)d_in[6];
    const float* lq1 = (const float*)d_in[7];
    const float* lk1 = (const float*)d_in[8];
    const float* lq2 = (const float*)d_in[9];
    const float* lk2 = (const float*)d_in[10];
    float* out = (float*)d_out;

    char* ws = (char*)d_ws;
    const size_t MB = 1ull << 20;
    bf16* wcT = (bf16*)(ws);
    bf16* cpj = (bf16*)(ws + 16 * MB);
    bf16* mg  = (bf16*)(ws);
    bf16* woT = (bf16*)(ws + 16 * MB);

    dim3 blk(256);
    transp<<<dim3(32, 32), blk, 0, stream>>>(Wq1, wcT, 1024, 1024, 1024, Q1O);
    transp<<<dim3(32, 32), blk, 0, stream>>>(Wq2, wcT, 1024, 1024, 1024, Q2O);
    transp<<<dim3(32, 32), blk, 0, stream>>>(Wk1, wcT, 1024, 1024, 1024, K1O);
    transp<<<dim3(32, 32), blk, 0, stream>>>(Wk2, wcT, 1024, 1024, 1024, K2O);
    transp<<<dim3(64, 32), blk, 0, stream>>>(Wv,  wcT, 1024, 2048, 1024, VO);
    mgemm<true, bf16><<<dim3((6144 / 128) * (4096 / 128)), blk, 0, stream>>>(
        x, wcT, cpj, 4096, 6144, 1024);
    attn_mfma<<<dim3(NB * NH * (SS / 64)), blk, 0, stream>>>(
        cpj, lq1, lk1, lq2, lk2, mg);
    transp<<<dim3(32, 64), blk, 0, stream>>>(Wo, woT, 2048, 1024, 2048, 0);
    mgemm<false, float><<<dim3((1024 / 128) * (4096 / 128)), blk, 0, stream>>>(
        mg, woT, out, 4096, 1024, 2048);
}